// Round 5
// baseline (370.845 us; speedup 1.0000x reference)
//
#include <hip/hip_runtime.h>

// ---------- problem constants ----------
constexpr int T_SEQ = 2048;
constexpr int CDIM  = 768;
constexpr int HEADS = 12;
constexpr int DH    = 64;
constexpr int BATCH = 2;
constexpr int BH_TOT = BATCH * HEADS;   // 24
constexpr int NROWS  = BATCH * T_SEQ;   // 4096
constexpr int JS     = 2;               // j-chunk split in fused_pv
constexpr float RMS_EPS = 1.1920929e-07f;  // np.finfo(float32).eps

typedef __attribute__((ext_vector_type(8))) short bf16x8;
typedef __attribute__((ext_vector_type(4))) float f32x4;
typedef __attribute__((ext_vector_type(4))) unsigned int u32x4;

__device__ __forceinline__ unsigned short f2bf(float f) {
    union { float f; unsigned int u; } v; v.f = f;
    unsigned int u = v.u;
    unsigned int r = (u + 0x7fffu + ((u >> 16) & 1u)) >> 16;  // RNE
    return (unsigned short)r;
}
__device__ __forceinline__ float b2f(unsigned short h) {
    union { unsigned int u; float f; } v; v.u = ((unsigned int)h) << 16;
    return v.f;
}
// packed RNE f32x2 -> bf16x2
__device__ __forceinline__ unsigned int cvt_pk_bf16(float lo, float hi) {
    unsigned int r;
    asm("v_cvt_pk_bf16_f32 %0, %1, %2" : "=v"(r) : "v"(lo), "v"(hi));
    return r;
}

// ---------- prep: split x and W into bf16 hi/lo; build W^T splits ----------
__global__ __launch_bounds__(256) void prep_kernel(
    const float* __restrict__ x, const float* __restrict__ W,
    unsigned short* __restrict__ xh, unsigned short* __restrict__ xl,
    unsigned short* __restrict__ Wh, unsigned short* __restrict__ Wl,
    unsigned short* __restrict__ WTh, unsigned short* __restrict__ WTl)
{
    const size_t NC = (size_t)NROWS * CDIM;
    const size_t WSZ = (size_t)CDIM * CDIM;
    size_t stride = (size_t)gridDim.x * blockDim.x;
    for (size_t i = (size_t)blockIdx.x * blockDim.x + threadIdx.x; i < NC; i += stride) {
        float v = x[i];
        unsigned short h = f2bf(v);
        xh[i] = h; xl[i] = f2bf(v - b2f(h));
    }
    for (size_t i = (size_t)blockIdx.x * blockDim.x + threadIdx.x; i < WSZ; i += stride) {
        float v = W[i];
        unsigned short h = f2bf(v);
        unsigned short l = f2bf(v - b2f(h));
        Wh[i] = h; Wl[i] = l;
        size_t k = i / CDIM, c = i % CDIM;
        WTh[c * CDIM + k] = h; WTl[c * CDIM + k] = l;
    }
}

// ---------- NT split-bf16 MFMA GEMM: C[M,N] = A[M,K] * B[N,K]^T ----------
__global__ __launch_bounds__(256) void gemm_nt_split(
    const unsigned short* __restrict__ Ah, const unsigned short* __restrict__ Al,
    const unsigned short* __restrict__ Bh, const unsigned short* __restrict__ Bl,
    float* __restrict__ C, int M, int N, int K, int ldc)
{
    __shared__ unsigned short sAh[128 * 64], sAl[128 * 64], sBh[128 * 64], sBl[128 * 64];
    const int tid = threadIdx.x;
    const int lane = tid & 63;
    const int wv = tid >> 6;
    const int wr = wv >> 1, wc = wv & 1;
    const int M0 = blockIdx.y * 128, N0 = blockIdx.x * 128;

    f32x4 acc[4][4];
#pragma unroll
    for (int i = 0; i < 4; ++i)
#pragma unroll
        for (int j = 0; j < 4; ++j) acc[i][j] = (f32x4)0.0f;

    for (int k0 = 0; k0 < K; k0 += 64) {
        __syncthreads();
#pragma unroll
        for (int p = 0; p < 4; ++p) {
            int elem = (p * 256 + tid) * 8;
            int row = elem >> 6;
            int off = (elem * 2) ^ ((row & 7) << 4);
            size_t ga = (size_t)(M0 + row) * K + k0 + (elem & 63);
            size_t gb = (size_t)(N0 + row) * K + k0 + (elem & 63);
            *(u32x4*)((char*)sAh + off) = *(const u32x4*)&Ah[ga];
            *(u32x4*)((char*)sAl + off) = *(const u32x4*)&Al[ga];
            *(u32x4*)((char*)sBh + off) = *(const u32x4*)&Bh[gb];
            *(u32x4*)((char*)sBl + off) = *(const u32x4*)&Bl[gb];
        }
        __syncthreads();
#pragma unroll
        for (int ks = 0; ks < 2; ++ks) {
            const int ko = ks * 32 + (lane >> 4) * 8;
            bf16x8 ah[4], al[4], bh[4], bl[4];
#pragma unroll
            for (int mi = 0; mi < 4; ++mi) {
                int r = wr * 64 + mi * 16 + (lane & 15);
                int off = (r * 128 + ko * 2) ^ ((r & 7) << 4);
                ah[mi] = *(const bf16x8*)((char*)sAh + off);
                al[mi] = *(const bf16x8*)((char*)sAl + off);
            }
#pragma unroll
            for (int ni = 0; ni < 4; ++ni) {
                int r = wc * 64 + ni * 16 + (lane & 15);
                int off = (r * 128 + ko * 2) ^ ((r & 7) << 4);
                bh[ni] = *(const bf16x8*)((char*)sBh + off);
                bl[ni] = *(const bf16x8*)((char*)sBl + off);
            }
#pragma unroll
            for (int mi = 0; mi < 4; ++mi)
#pragma unroll
                for (int ni = 0; ni < 4; ++ni) {
                    acc[mi][ni] = __builtin_amdgcn_mfma_f32_16x16x32_bf16(ah[mi], bh[ni], acc[mi][ni], 0, 0, 0);
                    acc[mi][ni] = __builtin_amdgcn_mfma_f32_16x16x32_bf16(ah[mi], bl[ni], acc[mi][ni], 0, 0, 0);
                    acc[mi][ni] = __builtin_amdgcn_mfma_f32_16x16x32_bf16(al[mi], bh[ni], acc[mi][ni], 0, 0, 0);
                }
        }
    }
#pragma unroll
    for (int mi = 0; mi < 4; ++mi)
#pragma unroll
        for (int ni = 0; ni < 4; ++ni)
#pragma unroll
            for (int r = 0; r < 4; ++r) {
                int row = M0 + wr * 64 + mi * 16 + (lane >> 4) * 4 + r;
                int col = N0 + wc * 64 + ni * 16 + (lane & 15);
                C[(size_t)row * ldc + col] = acc[mi][ni][r];
            }
}

// ---------- fused RMSNorm + QKV write (plain bf16 q,k,v) ----------
__global__ __launch_bounds__(256) void rmsqkv_kernel(
    const float* __restrict__ wbuf,
    const float* __restrict__ g1, const float* __restrict__ g2, const float* __restrict__ g3,
    unsigned short* __restrict__ qb, unsigned short* __restrict__ kb,
    unsigned short* __restrict__ vb)
{
    const int lane = threadIdx.x & 63;
    const int wv = threadIdx.x >> 6;
    const int ridx = blockIdx.x * 4 + wv;
    const int bt = ridx / HEADS;
    const int h = ridx % HEADS;
    const int b = bt >> 11, t = bt & (T_SEQ - 1);

    float v = wbuf[(size_t)bt * CDIM + h * DH + lane];
    float ss = v * v;
#pragma unroll
    for (int m = 32; m; m >>= 1) ss += __shfl_xor(ss, m);
    float r = rsqrtf(ss * (1.0f / 64.0f) + RMS_EPS);
    float wn = v * r;

    size_t o = ((size_t)(b * HEADS + h) * T_SEQ + t) * DH + lane;
    qb[o] = f2bf(wn * g1[lane]);
    kb[o] = f2bf(wn * g2[lane]);
    vb[o] = f2bf(wn * g3[lane]);
}

// ---------- transpose v [bh][t][f] -> vT [bh][f][t] ----------
__global__ __launch_bounds__(256) void vtrans_kernel(
    const unsigned short* __restrict__ vb, unsigned short* __restrict__ vT)
{
    __shared__ unsigned short tile[64][65];
    const int bh = blockIdx.y, t0 = blockIdx.x * 64;
    const int tid = threadIdx.x;
    const int c = tid & 63, r4 = tid >> 6;
#pragma unroll
    for (int i = 0; i < 16; ++i) {
        int rr = r4 + i * 4;
        tile[rr][c] = vb[((size_t)bh * T_SEQ + t0 + rr) * DH + c];
    }
    __syncthreads();
#pragma unroll
    for (int i = 0; i < 16; ++i) {
        int ff = r4 + i * 4;
        vT[((size_t)bh * DH + ff) * T_SEQ + t0 + c] = tile[c][ff];
    }
}

// ---------- pass 1: row/col sums of E = exp(QK^T/8) -----------------------
// grid (T/128 j-tiles, 4 i-chunks, BH). 4 waves; wave w owns j rows w*32..+32,
// K fragments held in registers across the block. No LDS, no barriers:
// Q fragment loads are identical across waves -> L1-served.
__global__ __launch_bounds__(256) void sums_kernel(
    const unsigned short* __restrict__ qb, const unsigned short* __restrict__ kb,
    float* __restrict__ rowsum, float* __restrict__ colsum)
{
    const int tid = threadIdx.x;
    const int lane = tid & 63;
    const int w = tid >> 6;
    const int li = lane & 15;
    const int g = lane >> 4;
    const int bh = blockIdx.z;
    const int J0 = blockIdx.x * 128;
    const int IC = blockIdx.y * 512;

    // this wave's K rows (A-operand), live in registers for the whole block
    bf16x8 kf[2][2];
#pragma unroll
    for (int jb = 0; jb < 2; ++jb)
#pragma unroll
        for (int ks = 0; ks < 2; ++ks)
            kf[jb][ks] = *(const bf16x8*)&kb[((size_t)bh * T_SEQ + J0 + w * 32 + jb * 16 + li) * DH
                                            + ks * 32 + g * 8];

    float csum[2][4];
#pragma unroll
    for (int jb = 0; jb < 2; ++jb)
#pragma unroll
        for (int r = 0; r < 4; ++r) csum[jb][r] = 0.0f;

    for (int it = 0; it < 4; ++it) {
        const int I0 = IC + it * 128;
#pragma unroll
        for (int half = 0; half < 2; ++half) {
            f32x4 acc[2][4];
#pragma unroll
            for (int jb = 0; jb < 2; ++jb)
#pragma unroll
                for (int ib = 0; ib < 4; ++ib) acc[jb][ib] = (f32x4)0.0f;
#pragma unroll
            for (int ks = 0; ks < 2; ++ks)
#pragma unroll
                for (int ib = 0; ib < 4; ++ib) {
                    bf16x8 qf = *(const bf16x8*)&qb[((size_t)bh * T_SEQ + I0 + half * 64 + ib * 16 + li) * DH
                                                    + ks * 32 + g * 8];
#pragma unroll
                    for (int jb = 0; jb < 2; ++jb)
                        acc[jb][ib] = __builtin_amdgcn_mfma_f32_16x16x32_bf16(kf[jb][ks], qf, acc[jb][ib], 0, 0, 0);
                }
            // exp; col partials in regs; row partials via shfl + atomics
#pragma unroll
            for (int ib = 0; ib < 4; ++ib) {
                float rp = 0.0f;
#pragma unroll
                for (int jb = 0; jb < 2; ++jb)
#pragma unroll
                    for (int r = 0; r < 4; ++r) {
                        float e = __expf(acc[jb][ib][r] * 0.125f);
                        csum[jb][r] += e;
                        rp += e;
                    }
                rp += __shfl_xor(rp, 16);
                rp += __shfl_xor(rp, 32);      // sum over this wave's 32 j
                if (g == 0)
                    atomicAdd(&rowsum[(size_t)bh * T_SEQ + I0 + half * 64 + ib * 16 + li], rp);
            }
        }
    }
    // colsum: reduce over the 16 i-lanes, one atomic per j
#pragma unroll
    for (int jb = 0; jb < 2; ++jb)
#pragma unroll
        for (int r = 0; r < 4; ++r) {
            float c = csum[jb][r];
            c += __shfl_xor(c, 1); c += __shfl_xor(c, 2);
            c += __shfl_xor(c, 4); c += __shfl_xor(c, 8);
            if (li == 0)
                atomicAdd(&colsum[(size_t)bh * T_SEQ + J0 + w * 32 + jb * 16 + g * 4 + r], c);
        }
}

// ---------- 1/x for row/col sums ----------
__global__ __launch_bounds__(256) void inv_kernel(
    const float* __restrict__ rs, const float* __restrict__ cs,
    float* __restrict__ ri, float* __restrict__ ci_, int n)
{
    int i = blockIdx.x * 256 + threadIdx.x;
    if (i < n) { ri[i] = 1.0f / rs[i]; ci_[i] = 1.0f / cs[i]; }
}

// ---------- pass 2: swapped QK^T + scale + PV, j-split, f32 partial out ----
// grid (T/64 i-tiles, JS j-chunks, BH). 4 waves, wave w owns 16 i-rows.
// No K staging (all waves read identical K/V addresses -> L1), no barriers;
// sP rows are wave-private (same-wave ds ordering via lgkmcnt).
__global__ __launch_bounds__(256) void fused_pv_kernel(
    const unsigned short* __restrict__ qb, const unsigned short* __restrict__ kb,
    const unsigned short* __restrict__ vT,
    const float* __restrict__ rowinv, const float* __restrict__ colinv,
    float* __restrict__ ypart)
{
    __shared__ unsigned short sP[64 * 128];   // 16 KB, rows private per wave

    const int tid = threadIdx.x;
    const int lane = tid & 63;
    const int w = tid >> 6;
    const int li = lane & 15;
    const int g = lane >> 4;
    const int bh = blockIdx.z;
    const int jc = blockIdx.y;
    const int I0 = blockIdx.x * 64;
    const int J0 = jc * (T_SEQ / JS);

    // Q fragments in registers, loaded once
    const int qrow = I0 + w * 16 + li;
    bf16x8 qf[2];
#pragma unroll
    for (int ks = 0; ks < 2; ++ks)
        qf[ks] = *(const bf16x8*)&qb[((size_t)bh * T_SEQ + qrow) * DH + ks * 32 + g * 8];
    const float rv = rowinv[bh * T_SEQ + qrow];

    const int prow = w * 16 + li;
    const int pkey = (prow & 7) << 4;

    f32x4 accy[4];
#pragma unroll
    for (int i = 0; i < 4; ++i) accy[i] = (f32x4)0.0f;

    const unsigned short* kt0 = &kb[((size_t)bh * T_SEQ + J0) * DH];
    for (int jt = 0; jt < T_SEQ / JS / 128; ++jt) {
        const unsigned short* kt = kt0 + (size_t)jt * 128 * DH;

        // swapped QK^T: accs[jb] rows = j, cols = i(li); K direct from global
        f32x4 accs[8];
#pragma unroll
        for (int jb = 0; jb < 8; ++jb) accs[jb] = (f32x4)0.0f;
#pragma unroll
        for (int ks = 0; ks < 2; ++ks) {
#pragma unroll
            for (int jb = 0; jb < 8; ++jb) {
                bf16x8 kf = *(const bf16x8*)&kt[(jb * 16 + li) * DH + ks * 32 + g * 8];
                accs[jb] = __builtin_amdgcn_mfma_f32_16x16x32_bf16(kf, qf[ks], accs[jb], 0, 0, 0);
            }
        }

        // P = exp(S/8)*(rinv_i + cinv_j) -> packed bf16 -> sP (own rows)
#pragma unroll
        for (int jb = 0; jb < 8; ++jb) {
            f32x4 cv = *(const f32x4*)&colinv[(size_t)bh * T_SEQ + J0 + jt * 128 + jb * 16 + g * 4];
            float p0 = __expf(accs[jb][0] * 0.125f) * (rv + cv[0]);
            float p1 = __expf(accs[jb][1] * 0.125f) * (rv + cv[1]);
            float p2 = __expf(accs[jb][2] * 0.125f) * (rv + cv[2]);
            float p3 = __expf(accs[jb][3] * 0.125f) * (rv + cv[3]);
            uint2 pw;
            pw.x = cvt_pk_bf16(p0, p1);
            pw.y = cvt_pk_bf16(p2, p3);
            int off = (prow * 256 + jb * 32 + g * 8) ^ pkey;
            *(uint2*)((char*)sP + off) = pw;
        }

        // PV: y[i][f] += P[i][j] * V^T[f][j]; V direct from global
#pragma unroll
        for (int ks2 = 0; ks2 < 4; ++ks2) {
            bf16x8 pf = *(const bf16x8*)((char*)sP + ((prow * 256 + ks2 * 64 + g * 16) ^ pkey));
#pragma unroll
            for (int ni = 0; ni < 4; ++ni) {
                bf16x8 vf = *(const bf16x8*)&vT[((size_t)bh * DH + ni * 16 + li) * T_SEQ
                                                + J0 + jt * 128 + ks2 * 32 + g * 8];
                accy[ni] = __builtin_amdgcn_mfma_f32_16x16x32_bf16(pf, vf, accy[ni], 0, 0, 0);
            }
        }
    }

    // store f32 partial: ypart[jc][bh][i][f]
#pragma unroll
    for (int ni = 0; ni < 4; ++ni)
#pragma unroll
        for (int r = 0; r < 4; ++r) {
            int i = I0 + w * 16 + g * 4 + r;
            int f = ni * 16 + li;
            ypart[(((size_t)jc * BH_TOT + bh) * T_SEQ + i) * DH + f] = accy[ni][r];
        }
}

// ---------- reduce JS partials -> split bf16 y ----------
__global__ __launch_bounds__(256) void reduce_kernel(
    const float* __restrict__ ypart,
    unsigned short* __restrict__ yh, unsigned short* __restrict__ yl)
{
    const size_t STR = (size_t)BH_TOT * T_SEQ * DH;
    size_t idx = (size_t)blockIdx.x * 256 + threadIdx.x;   // one per 4 elems
    if (idx >= STR / 4) return;
    f32x4 a = *(const f32x4*)&ypart[idx * 4];
    f32x4 b = *(const f32x4*)&ypart[STR + idx * 4];
    int e = (int)(idx * 4);
    int f = e & 63;
    int rrow = e >> 6;
    int t = rrow & (T_SEQ - 1);
    int bh = rrow >> 11;
    int b_ = bh / HEADS, h = bh % HEADS;
    size_t o = ((size_t)b_ * T_SEQ + t) * CDIM + h * DH + f;
#pragma unroll
    for (int q = 0; q < 4; ++q) {
        float s = a[q] + b[q];
        unsigned short hi = f2bf(s);
        yh[o + q] = hi;
        yl[o + q] = f2bf(s - b2f(hi));
    }
}

// ---------- host ----------
extern "C" void kernel_launch(void* const* d_in, const int* in_sizes, int n_in,
                              void* d_out, int out_size, void* d_ws, size_t ws_size,
                              hipStream_t stream)
{
    const float* x  = (const float*)d_in[0];
    const float* W  = (const float*)d_in[1];
    const float* g1 = (const float*)d_in[2];
    const float* g2 = (const float*)d_in[3];
    const float* g3 = (const float*)d_in[4];
    float* out = (float*)d_out;

    char* p = (char*)d_ws;
    auto alloc = [&](size_t bytes) -> void* {
        void* r = (void*)p;
        p += (bytes + 255) & ~(size_t)255;
        return r;
    };
    const size_t NC  = (size_t)NROWS * CDIM;
    const size_t WSZ = (size_t)CDIM * CDIM;
    const size_t QSZ = (size_t)BH_TOT * T_SEQ * DH;

    // NOTE: xh/xl/wbuf (25.17 MB, dead after rmsqkv) exactly alias ypart
    // (JS * BH * T * DH * 4 = 25.17 MB, first used in fused_pv).
    unsigned short* xh  = (unsigned short*)alloc(NC * 2);
    unsigned short* xl  = (unsigned short*)alloc(NC * 2);
    float*          wbuf = (float*)alloc(NC * 4);
    float*          ypart = (float*)d_ws;   // alias of [xh, xl, wbuf]
    unsigned short* Wh  = (unsigned short*)alloc(WSZ * 2);
    unsigned short* Wl  = (unsigned short*)alloc(WSZ * 2);
    unsigned short* WTh = (unsigned short*)alloc(WSZ * 2);
    unsigned short* WTl = (unsigned short*)alloc(WSZ * 2);
    unsigned short* qb  = (unsigned short*)alloc(QSZ * 2);
    unsigned short* kb  = (unsigned short*)alloc(QSZ * 2);
    unsigned short* vb  = (unsigned short*)alloc(QSZ * 2);
    unsigned short* vT  = (unsigned short*)alloc(QSZ * 2);
    unsigned short* yh  = (unsigned short*)alloc(NC * 2);
    unsigned short* yl  = (unsigned short*)alloc(NC * 2);
    float* rowsum = (float*)alloc((size_t)BH_TOT * T_SEQ * 4);
    float* colsum = (float*)alloc((size_t)BH_TOT * T_SEQ * 4);
    float* rowinv = (float*)alloc((size_t)BH_TOT * T_SEQ * 4);
    float* colinv = (float*)alloc((size_t)BH_TOT * T_SEQ * 4);

    prep_kernel<<<2048, 256, 0, stream>>>(x, W, xh, xl, Wh, Wl, WTh, WTl);
    gemm_nt_split<<<dim3(CDIM / 128, NROWS / 128), 256, 0, stream>>>(
        xh, xl, Wh, Wl, wbuf, NROWS, CDIM, CDIM, CDIM);
    rmsqkv_kernel<<<(NROWS * HEADS) / 4, 256, 0, stream>>>(
        wbuf, g1, g2, g3, qb, kb, vb);
    vtrans_kernel<<<dim3(T_SEQ / 64, BH_TOT), 256, 0, stream>>>(vb, vT);

    hipMemsetAsync(rowsum, 0, (size_t)BH_TOT * T_SEQ * 4, stream);
    hipMemsetAsync(colsum, 0, (size_t)BH_TOT * T_SEQ * 4, stream);
    sums_kernel<<<dim3(T_SEQ / 128, 4, BH_TOT), 256, 0, stream>>>(
        qb, kb, rowsum, colsum);
    int n = BH_TOT * T_SEQ;
    inv_kernel<<<(n + 255) / 256, 256, 0, stream>>>(rowsum, colsum, rowinv, colinv, n);

    fused_pv_kernel<<<dim3(T_SEQ / 64, JS, BH_TOT), 256, 0, stream>>>(
        qb, kb, vT, rowinv, colinv, ypart);
    {
        size_t n4 = (size_t)BH_TOT * T_SEQ * DH / 4;
        reduce_kernel<<<(unsigned)((n4 + 255) / 256), 256, 0, stream>>>(ypart, yh, yl);
    }

    gemm_nt_split<<<dim3(CDIM / 128, NROWS / 128), 256, 0, stream>>>(
        yh, yl, WTh, WTl, out, NROWS, CDIM, CDIM, CDIM);
}

// Round 6
// 175.032 us; speedup vs baseline: 2.1187x; 2.1187x over previous
//
#include <hip/hip_runtime.h>

// ---------- problem constants ----------
constexpr int T_SEQ = 2048;
constexpr int CDIM  = 768;
constexpr int HEADS = 12;
constexpr int DH    = 64;
constexpr int BATCH = 2;
constexpr int BH_TOT = BATCH * HEADS;   // 24
constexpr int NROWS  = BATCH * T_SEQ;   // 4096
constexpr int JS     = 2;               // j-chunk split in fused_pv
constexpr float RMS_EPS = 1.1920929e-07f;  // np.finfo(float32).eps

typedef __attribute__((ext_vector_type(8))) short bf16x8;
typedef __attribute__((ext_vector_type(4))) float f32x4;
typedef __attribute__((ext_vector_type(4))) unsigned int u32x4;

__device__ __forceinline__ unsigned short f2bf(float f) {
    union { float f; unsigned int u; } v; v.f = f;
    unsigned int u = v.u;
    unsigned int r = (u + 0x7fffu + ((u >> 16) & 1u)) >> 16;  // RNE
    return (unsigned short)r;
}
__device__ __forceinline__ float b2f(unsigned short h) {
    union { unsigned int u; float f; } v; v.u = ((unsigned int)h) << 16;
    return v.f;
}
// packed RNE f32x2 -> bf16x2
__device__ __forceinline__ unsigned int cvt_pk_bf16(float lo, float hi) {
    unsigned int r;
    asm("v_cvt_pk_bf16_f32 %0, %1, %2" : "=v"(r) : "v"(lo), "v"(hi));
    return r;
}
// async 16B global->LDS (linear LDS dest; pre-swizzle the SOURCE)
__device__ __forceinline__ void gld_lds16(const void* g, void* l) {
    __builtin_amdgcn_global_load_lds(
        (const __attribute__((address_space(1))) void*)g,
        (__attribute__((address_space(3))) void*)l, 16, 0, 0);
}
// stage a 16KB tile (128 rows x 64 bf16, contiguous rows) into LDS,
// XOR-swizzled: phys = linear ^ ((row&7)<<4) via inverse-swizzled source.
__device__ __forceinline__ void stage16k(const unsigned short* gbase, unsigned short* lbase, int tid) {
#pragma unroll
    for (int p = 0; p < 4; ++p) {
        int d = (p * 256 + tid) * 16;
        int gb = d ^ (((d >> 7) & 7) << 4);
        gld_lds16((const char*)gbase + gb, (char*)lbase + d);
    }
}
// stage a 16KB V tile (64 f-rows x 128 j bf16; global row stride T_SEQ*2 bytes)
// LDS layout: 64 rows x 256B, phys = linear ^ ((f&7)<<4)
__device__ __forceinline__ void stageV16k(const unsigned short* vbase, int jbyte0,
                                          unsigned short* lbase, int tid) {
#pragma unroll
    for (int p = 0; p < 4; ++p) {
        int d = (p * 256 + tid) * 16;
        int f = d >> 8;
        int cb = (d & 255) ^ ((f & 7) << 4);
        gld_lds16((const char*)vbase + (size_t)f * (T_SEQ * 2) + jbyte0 + cb,
                  (char*)lbase + d);
    }
}

// ---------- prep: split x and W into bf16 hi/lo; build W^T splits ----------
__global__ __launch_bounds__(256) void prep_kernel(
    const float* __restrict__ x, const float* __restrict__ W,
    unsigned short* __restrict__ xh, unsigned short* __restrict__ xl,
    unsigned short* __restrict__ Wh, unsigned short* __restrict__ Wl,
    unsigned short* __restrict__ WTh, unsigned short* __restrict__ WTl)
{
    const size_t NC = (size_t)NROWS * CDIM;
    const size_t WSZ = (size_t)CDIM * CDIM;
    size_t stride = (size_t)gridDim.x * blockDim.x;
    for (size_t i = (size_t)blockIdx.x * blockDim.x + threadIdx.x; i < NC; i += stride) {
        float v = x[i];
        unsigned short h = f2bf(v);
        xh[i] = h; xl[i] = f2bf(v - b2f(h));
    }
    for (size_t i = (size_t)blockIdx.x * blockDim.x + threadIdx.x; i < WSZ; i += stride) {
        float v = W[i];
        unsigned short h = f2bf(v);
        unsigned short l = f2bf(v - b2f(h));
        Wh[i] = h; Wl[i] = l;
        size_t k = i / CDIM, c = i % CDIM;
        WTh[c * CDIM + k] = h; WTl[c * CDIM + k] = l;
    }
}

// ---------- 64x64-tile NT MFMA GEMM: C[M,N] = A[M,K]*B[N,K]^T --------------
// SPLIT: acc += Ah*Bh + Ah*Bl + Al*Bh ; else plain bf16. grid (N/64, M/64).
template<bool SPLIT>
__global__ __launch_bounds__(256) void gemm64_nt(
    const unsigned short* __restrict__ Ah, const unsigned short* __restrict__ Al,
    const unsigned short* __restrict__ Bh, const unsigned short* __restrict__ Bl,
    float* __restrict__ C, int M, int N, int K, int ldc)
{
    __shared__ unsigned short sAh[64 * 64], sBh[64 * 64];
    __shared__ unsigned short sAl[64 * 64], sBl[64 * 64];   // unused if !SPLIT
    const int tid = threadIdx.x;
    const int lane = tid & 63;
    const int wv = tid >> 6;
    const int wr = wv >> 1, wc = wv & 1;
    const int li = lane & 15, g = lane >> 4;
    const int M0 = blockIdx.y * 64, N0 = blockIdx.x * 64;

    f32x4 acc[2][2];
#pragma unroll
    for (int i = 0; i < 2; ++i)
#pragma unroll
        for (int j = 0; j < 2; ++j) acc[i][j] = (f32x4)0.0f;

    for (int k0 = 0; k0 < K; k0 += 64) {
        __syncthreads();
#pragma unroll
        for (int p = 0; p < 2; ++p) {
            int dd = tid * 16 + p * 4096;
            int row = dd >> 7;
            int cb = (dd & 127) ^ ((row & 7) << 4);
            size_t abyte = ((size_t)(M0 + row) * K + k0) * 2 + cb;
            size_t bbyte = ((size_t)(N0 + row) * K + k0) * 2 + cb;
            gld_lds16((const char*)Ah + abyte, (char*)sAh + dd);
            gld_lds16((const char*)Bh + bbyte, (char*)sBh + dd);
            if constexpr (SPLIT) {
                gld_lds16((const char*)Al + abyte, (char*)sAl + dd);
                gld_lds16((const char*)Bl + bbyte, (char*)sBl + dd);
            }
        }
        __syncthreads();
#pragma unroll
        for (int ks = 0; ks < 2; ++ks) {
            const int ko = ks * 32 + g * 8;
            bf16x8 ah[2], bh[2], al[2], bl[2];
#pragma unroll
            for (int mi = 0; mi < 2; ++mi) {
                int r = wr * 32 + mi * 16 + li;
                int off = (r * 128 + ko * 2) ^ ((r & 7) << 4);
                ah[mi] = *(const bf16x8*)((char*)sAh + off);
                if constexpr (SPLIT) al[mi] = *(const bf16x8*)((char*)sAl + off);
            }
#pragma unroll
            for (int ni = 0; ni < 2; ++ni) {
                int r = wc * 32 + ni * 16 + li;
                int off = (r * 128 + ko * 2) ^ ((r & 7) << 4);
                bh[ni] = *(const bf16x8*)((char*)sBh + off);
                if constexpr (SPLIT) bl[ni] = *(const bf16x8*)((char*)sBl + off);
            }
#pragma unroll
            for (int mi = 0; mi < 2; ++mi)
#pragma unroll
                for (int ni = 0; ni < 2; ++ni) {
                    acc[mi][ni] = __builtin_amdgcn_mfma_f32_16x16x32_bf16(ah[mi], bh[ni], acc[mi][ni], 0, 0, 0);
                    if constexpr (SPLIT) {
                        acc[mi][ni] = __builtin_amdgcn_mfma_f32_16x16x32_bf16(ah[mi], bl[ni], acc[mi][ni], 0, 0, 0);
                        acc[mi][ni] = __builtin_amdgcn_mfma_f32_16x16x32_bf16(al[mi], bh[ni], acc[mi][ni], 0, 0, 0);
                    }
                }
        }
    }
#pragma unroll
    for (int mi = 0; mi < 2; ++mi)
#pragma unroll
        for (int ni = 0; ni < 2; ++ni)
#pragma unroll
            for (int r = 0; r < 4; ++r) {
                int row = M0 + wr * 32 + mi * 16 + g * 4 + r;
                int col = N0 + wc * 32 + ni * 16 + li;
                C[(size_t)row * ldc + col] = acc[mi][ni][r];
            }
}

// ---------- fused RMSNorm + QKV write (plain bf16 q,k,v) ----------
__global__ __launch_bounds__(256) void rmsqkv_kernel(
    const float* __restrict__ wbuf,
    const float* __restrict__ g1, const float* __restrict__ g2, const float* __restrict__ g3,
    unsigned short* __restrict__ qb, unsigned short* __restrict__ kb,
    unsigned short* __restrict__ vb)
{
    const int lane = threadIdx.x & 63;
    const int wv = threadIdx.x >> 6;
    const int ridx = blockIdx.x * 4 + wv;
    const int bt = ridx / HEADS;
    const int h = ridx % HEADS;
    const int b = bt >> 11, t = bt & (T_SEQ - 1);

    float v = wbuf[(size_t)bt * CDIM + h * DH + lane];
    float ss = v * v;
#pragma unroll
    for (int m = 32; m; m >>= 1) ss += __shfl_xor(ss, m);
    float r = rsqrtf(ss * (1.0f / 64.0f) + RMS_EPS);
    float wn = v * r;

    size_t o = ((size_t)(b * HEADS + h) * T_SEQ + t) * DH + lane;
    qb[o] = f2bf(wn * g1[lane]);
    kb[o] = f2bf(wn * g2[lane]);
    vb[o] = f2bf(wn * g3[lane]);
}

// ---------- transpose v [bh][t][f] -> vT [bh][f][t] ----------
__global__ __launch_bounds__(256) void vtrans_kernel(
    const unsigned short* __restrict__ vb, unsigned short* __restrict__ vT)
{
    __shared__ unsigned short tile[64][65];
    const int bh = blockIdx.y, t0 = blockIdx.x * 64;
    const int tid = threadIdx.x;
    const int c = tid & 63, r4 = tid >> 6;
#pragma unroll
    for (int i = 0; i < 16; ++i) {
        int rr = r4 + i * 4;
        tile[rr][c] = vb[((size_t)bh * T_SEQ + t0 + rr) * DH + c];
    }
    __syncthreads();
#pragma unroll
    for (int i = 0; i < 16; ++i) {
        int ff = r4 + i * 4;
        vT[((size_t)bh * DH + ff) * T_SEQ + t0 + c] = tile[c][ff];
    }
}

// ---------- pass 1: row/col sums of E = exp(QK^T/8) -----------------------
// grid (T/128 j-tiles, 4 i-chunks, BH). Wave w owns j rows w*32..+32 (K frags
// in registers, loaded once direct from global). sQ double-buffered via
// gld_lds; stage issued BEFORE compute -> drain hidden; 1 barrier/i-tile.
__global__ __launch_bounds__(256) void sums_kernel(
    const unsigned short* __restrict__ qb, const unsigned short* __restrict__ kb,
    float* __restrict__ rowsum, float* __restrict__ colsum)
{
    __shared__ unsigned short sQ[2][128 * 64];
    const int tid = threadIdx.x;
    const int lane = tid & 63;
    const int w = tid >> 6;
    const int li = lane & 15;
    const int g = lane >> 4;
    const int bh = blockIdx.z;
    const int J0 = blockIdx.x * 128;
    const int IC = blockIdx.y * 512;

    // K fragments (one-time, latency-tolerant scatter)
    bf16x8 kf[2][2];
#pragma unroll
    for (int jb = 0; jb < 2; ++jb)
#pragma unroll
        for (int ks = 0; ks < 2; ++ks)
            kf[jb][ks] = *(const bf16x8*)&kb[((size_t)bh * T_SEQ + J0 + w * 32 + jb * 16 + li) * DH
                                            + ks * 32 + g * 8];

    stage16k(&qb[((size_t)bh * T_SEQ + IC) * DH], sQ[0], tid);
    __syncthreads();

    float csum[2][4];
#pragma unroll
    for (int jb = 0; jb < 2; ++jb)
#pragma unroll
        for (int r = 0; r < 4; ++r) csum[jb][r] = 0.0f;

    for (int it = 0; it < 4; ++it) {
        const int I0 = IC + it * 128;
        if (it + 1 < 4)
            stage16k(&qb[((size_t)bh * T_SEQ + I0 + 128) * DH], sQ[(it + 1) & 1], tid);
        const unsigned short* q = sQ[it & 1];

#pragma unroll
        for (int half = 0; half < 2; ++half) {
            f32x4 acc[2][4];
#pragma unroll
            for (int jb = 0; jb < 2; ++jb)
#pragma unroll
                for (int ib = 0; ib < 4; ++ib) acc[jb][ib] = (f32x4)0.0f;
#pragma unroll
            for (int ks = 0; ks < 2; ++ks) {
                const int ko = ks * 32 + g * 8;
#pragma unroll
                for (int ib = 0; ib < 4; ++ib) {
                    int qr = half * 64 + ib * 16 + li;
                    bf16x8 qf = *(const bf16x8*)((const char*)q + ((qr * 128 + ko * 2) ^ ((qr & 7) << 4)));
#pragma unroll
                    for (int jb = 0; jb < 2; ++jb)
                        acc[jb][ib] = __builtin_amdgcn_mfma_f32_16x16x32_bf16(kf[jb][ks], qf, acc[jb][ib], 0, 0, 0);
                }
            }
#pragma unroll
            for (int ib = 0; ib < 4; ++ib) {
                float rp = 0.0f;
#pragma unroll
                for (int jb = 0; jb < 2; ++jb)
#pragma unroll
                    for (int r = 0; r < 4; ++r) {
                        float e = __expf(acc[jb][ib][r] * 0.125f);
                        csum[jb][r] += e;
                        rp += e;
                    }
                rp += __shfl_xor(rp, 16);
                rp += __shfl_xor(rp, 32);      // sum over this wave's 32 j
                if (g == 0)
                    atomicAdd(&rowsum[(size_t)bh * T_SEQ + I0 + half * 64 + ib * 16 + li], rp);
            }
        }
        __syncthreads();   // drains next-tile stage (hidden under compute); buffer swap
    }
    // colsum: reduce over the 16 i-lanes, one atomic per j
#pragma unroll
    for (int jb = 0; jb < 2; ++jb)
#pragma unroll
        for (int r = 0; r < 4; ++r) {
            float c = csum[jb][r];
            c += __shfl_xor(c, 1); c += __shfl_xor(c, 2);
            c += __shfl_xor(c, 4); c += __shfl_xor(c, 8);
            if (li == 0)
                atomicAdd(&colsum[(size_t)bh * T_SEQ + J0 + w * 32 + jb * 16 + g * 4 + r], c);
        }
}

// ---------- 1/x for row/col sums ----------
__global__ __launch_bounds__(256) void inv_kernel(
    const float* __restrict__ rs, const float* __restrict__ cs,
    float* __restrict__ ri, float* __restrict__ ci_, int n)
{
    int i = blockIdx.x * 256 + threadIdx.x;
    if (i < n) { ri[i] = 1.0f / rs[i]; ci_[i] = 1.0f / cs[i]; }
}

// ---------- pass 2: swapped QK^T + scale + PV, j-split, f32 partial out ----
// grid (T/64 i-tiles, JS j-chunks, BH). Wave w owns 16 i-rows. T14 schedule:
//   QK^T(sK) ; pack->sP ; sync(a) ; stageK(t+1) ; PV(sP,sV) ; sync(b) ; stageV(t+1)
// Every stage has a full compute phase before its draining barrier.
__global__ __launch_bounds__(256) void fused_pv_kernel(
    const unsigned short* __restrict__ qb, const unsigned short* __restrict__ kb,
    const unsigned short* __restrict__ vT,
    const float* __restrict__ rowinv, const float* __restrict__ colinv,
    float* __restrict__ ypart)
{
    __shared__ unsigned short sK[128 * 64];   // 16 KB
    __shared__ unsigned short sP[64 * 128];   // 16 KB, rows private per wave
    __shared__ unsigned short sV[64 * 128];   // 16 KB: [f][128 j]

    const int tid = threadIdx.x;
    const int lane = tid & 63;
    const int w = tid >> 6;
    const int li = lane & 15;
    const int g = lane >> 4;
    const int bh = blockIdx.z;
    const int jc = blockIdx.y;
    const int I0 = blockIdx.x * 64;
    const int J0 = jc * (T_SEQ / JS);
    constexpr int NT = T_SEQ / JS / 128;   // 8

    // Q fragments in registers, loaded once
    const int qrow = I0 + w * 16 + li;
    bf16x8 qf[2];
#pragma unroll
    for (int ks = 0; ks < 2; ++ks)
        qf[ks] = *(const bf16x8*)&qb[((size_t)bh * T_SEQ + qrow) * DH + ks * 32 + g * 8];
    const float rv = rowinv[bh * T_SEQ + qrow];

    const int prow = w * 16 + li;
    const int pkey = (prow & 7) << 4;

    f32x4 accy[4];
#pragma unroll
    for (int i = 0; i < 4; ++i) accy[i] = (f32x4)0.0f;

    const unsigned short* kt0 = &kb[((size_t)bh * T_SEQ + J0) * DH];
    const unsigned short* vb0 = &vT[(size_t)bh * DH * T_SEQ];

    // prologue: stage K(0) and V(0)
    stage16k(kt0, sK, tid);
    stageV16k(vb0, J0 * 2, sV, tid);
    __syncthreads();

    for (int jt = 0; jt < NT; ++jt) {
        // --- QK^T from sK (swapped: rows = j, cols = i) ---
        f32x4 accs[8];
#pragma unroll
        for (int jb = 0; jb < 8; ++jb) accs[jb] = (f32x4)0.0f;
#pragma unroll
        for (int ks = 0; ks < 2; ++ks) {
            const int ko = ks * 32 + g * 8;
#pragma unroll
            for (int jb = 0; jb < 8; ++jb) {
                int jr = jb * 16 + li;
                bf16x8 kfr = *(const bf16x8*)((char*)sK + ((jr * 128 + ko * 2) ^ ((jr & 7) << 4)));
                accs[jb] = __builtin_amdgcn_mfma_f32_16x16x32_bf16(kfr, qf[ks], accs[jb], 0, 0, 0);
            }
        }

        // --- pack: P = exp(S/8)*(rinv_i + cinv_j) -> bf16 -> sP (own rows) ---
#pragma unroll
        for (int jb = 0; jb < 8; ++jb) {
            f32x4 cv = *(const f32x4*)&colinv[(size_t)bh * T_SEQ + J0 + jt * 128 + jb * 16 + g * 4];
            float p0 = __expf(accs[jb][0] * 0.125f) * (rv + cv[0]);
            float p1 = __expf(accs[jb][1] * 0.125f) * (rv + cv[1]);
            float p2 = __expf(accs[jb][2] * 0.125f) * (rv + cv[2]);
            float p3 = __expf(accs[jb][3] * 0.125f) * (rv + cv[3]);
            uint2 pw;
            pw.x = cvt_pk_bf16(p0, p1);
            pw.y = cvt_pk_bf16(p2, p3);
            int off = (prow * 256 + jb * 32 + g * 8) ^ pkey;
            *(uint2*)((char*)sP + off) = pw;
        }

        __syncthreads();   // (a): all sK reads done; drains V(jt) stage from prev (b)
        if (jt + 1 < NT)
            stage16k(kt0 + (size_t)(jt + 1) * 128 * DH, sK, tid);

        // --- PV: y[i][f] += P[i][j] * V^T[f][j], both from LDS ---
#pragma unroll
        for (int ks2 = 0; ks2 < 4; ++ks2) {
            bf16x8 pf = *(const bf16x8*)((char*)sP + ((prow * 256 + ks2 * 64 + g * 16) ^ pkey));
#pragma unroll
            for (int ni = 0; ni < 4; ++ni) {
                int vrow = ni * 16 + li;
                bf16x8 vf = *(const bf16x8*)((char*)sV + ((vrow * 256 + ks2 * 64 + g * 16) ^ ((vrow & 7) << 4)));
                accy[ni] = __builtin_amdgcn_mfma_f32_16x16x32_bf16(pf, vf, accy[ni], 0, 0, 0);
            }
        }

        __syncthreads();   // (b): drains K(jt+1) stage (hidden under PV); sV reads done
        if (jt + 1 < NT)
            stageV16k(vb0, (J0 + (jt + 1) * 128) * 2, sV, tid);
    }

    // store f32 partial: ypart[jc][bh][i][f]
#pragma unroll
    for (int ni = 0; ni < 4; ++ni)
#pragma unroll
        for (int r = 0; r < 4; ++r) {
            int i = I0 + w * 16 + g * 4 + r;
            int f = ni * 16 + li;
            ypart[(((size_t)jc * BH_TOT + bh) * T_SEQ + i) * DH + f] = accy[ni][r];
        }
}

// ---------- reduce JS partials -> bf16 y ----------
__global__ __launch_bounds__(256) void reduce_kernel(
    const float* __restrict__ ypart, unsigned short* __restrict__ yh)
{
    const size_t STR = (size_t)BH_TOT * T_SEQ * DH;
    size_t idx = (size_t)blockIdx.x * 256 + threadIdx.x;   // one per 4 elems
    if (idx >= STR / 4) return;
    f32x4 a = *(const f32x4*)&ypart[idx * 4];
    f32x4 b = *(const f32x4*)&ypart[STR + idx * 4];
    int e = (int)(idx * 4);
    int f = e & 63;
    int rrow = e >> 6;
    int t = rrow & (T_SEQ - 1);
    int bh = rrow >> 11;
    int b_ = bh / HEADS, h = bh % HEADS;
    size_t o = ((size_t)b_ * T_SEQ + t) * CDIM + h * DH + f;
#pragma unroll
    for (int q = 0; q < 4; ++q)
        yh[o + q] = f2bf(a[q] + b[q]);
}

// ---------- host ----------
extern "C" void kernel_launch(void* const* d_in, const int* in_sizes, int n_in,
                              void* d_out, int out_size, void* d_ws, size_t ws_size,
                              hipStream_t stream)
{
    const float* x  = (const float*)d_in[0];
    const float* W  = (const float*)d_in[1];
    const float* g1 = (const float*)d_in[2];
    const float* g2 = (const float*)d_in[3];
    const float* g3 = (const float*)d_in[4];
    float* out = (float*)d_out;

    char* p = (char*)d_ws;
    auto alloc = [&](size_t bytes) -> void* {
        void* r = (void*)p;
        p += (bytes + 255) & ~(size_t)255;
        return r;
    };
    const size_t NC  = (size_t)NROWS * CDIM;
    const size_t WSZ = (size_t)CDIM * CDIM;
    const size_t QSZ = (size_t)BH_TOT * T_SEQ * DH;

    // NOTE: xh/xl/wbuf (25.17 MB, dead after rmsqkv) exactly alias ypart
    // (JS * BH * T * DH * 4 = 25.17 MB, first used in fused_pv).
    unsigned short* xh  = (unsigned short*)alloc(NC * 2);
    unsigned short* xl  = (unsigned short*)alloc(NC * 2);
    float*          wbuf = (float*)alloc(NC * 4);
    float*          ypart = (float*)d_ws;   // alias of [xh, xl, wbuf]
    unsigned short* Wh  = (unsigned short*)alloc(WSZ * 2);
    unsigned short* Wl  = (unsigned short*)alloc(WSZ * 2);
    unsigned short* WTh = (unsigned short*)alloc(WSZ * 2);
    unsigned short* WTl = (unsigned short*)alloc(WSZ * 2);
    unsigned short* qb  = (unsigned short*)alloc(QSZ * 2);
    unsigned short* kb  = (unsigned short*)alloc(QSZ * 2);
    unsigned short* vb  = (unsigned short*)alloc(QSZ * 2);
    unsigned short* vT  = (unsigned short*)alloc(QSZ * 2);
    unsigned short* yh  = (unsigned short*)alloc(NC * 2);
    float* rowsum = (float*)alloc((size_t)BH_TOT * T_SEQ * 4);
    float* colsum = (float*)alloc((size_t)BH_TOT * T_SEQ * 4);
    float* rowinv = (float*)alloc((size_t)BH_TOT * T_SEQ * 4);
    float* colinv = (float*)alloc((size_t)BH_TOT * T_SEQ * 4);

    prep_kernel<<<2048, 256, 0, stream>>>(x, W, xh, xl, Wh, Wl, WTh, WTl);
    gemm64_nt<true><<<dim3(CDIM / 64, NROWS / 64), 256, 0, stream>>>(
        xh, xl, Wh, Wl, wbuf, NROWS, CDIM, CDIM, CDIM);
    rmsqkv_kernel<<<(NROWS * HEADS) / 4, 256, 0, stream>>>(
        wbuf, g1, g2, g3, qb, kb, vb);
    vtrans_kernel<<<dim3(T_SEQ / 64, BH_TOT), 256, 0, stream>>>(vb, vT);

    hipMemsetAsync(rowsum, 0, (size_t)BH_TOT * T_SEQ * 4, stream);
    hipMemsetAsync(colsum, 0, (size_t)BH_TOT * T_SEQ * 4, stream);
    sums_kernel<<<dim3(T_SEQ / 128, 4, BH_TOT), 256, 0, stream>>>(
        qb, kb, rowsum, colsum);
    int n = BH_TOT * T_SEQ;
    inv_kernel<<<(n + 255) / 256, 256, 0, stream>>>(rowsum, colsum, rowinv, colinv, n);

    fused_pv_kernel<<<dim3(T_SEQ / 64, JS, BH_TOT), 256, 0, stream>>>(
        qb, kb, vT, rowinv, colinv, ypart);
    {
        size_t n4 = (size_t)BH_TOT * T_SEQ * DH / 4;
        reduce_kernel<<<(unsigned)((n4 + 255) / 256), 256, 0, stream>>>(ypart, yh);
    }

    gemm64_nt<false><<<dim3(CDIM / 64, NROWS / 64), 256, 0, stream>>>(
        yh, yh, WTh, WTh, out, NROWS, CDIM, CDIM, CDIM);
}

// Round 7
// 162.852 us; speedup vs baseline: 2.2772x; 1.0748x over previous
//
#include <hip/hip_runtime.h>

// ---------- problem constants ----------
constexpr int T_SEQ = 2048;
constexpr int CDIM  = 768;
constexpr int HEADS = 12;
constexpr int DH    = 64;
constexpr int BATCH = 2;
constexpr int BH_TOT = BATCH * HEADS;   // 24
constexpr int NROWS  = BATCH * T_SEQ;   // 4096
constexpr int JS     = 2;               // j-chunk split in fused_pv
constexpr float RMS_EPS = 1.1920929e-07f;  // np.finfo(float32).eps
// fold softmax scale into Q: S' = (q*QSCALE). k ; E = 2^(S') = e^(S/8)
constexpr float QSCALE = 0.18033688011112042f;  // 0.125 * log2(e)

typedef __attribute__((ext_vector_type(8))) short bf16x8;
typedef __attribute__((ext_vector_type(4))) float f32x4;
typedef __attribute__((ext_vector_type(4))) unsigned int u32x4;

__device__ __forceinline__ unsigned short f2bf(float f) {
    union { float f; unsigned int u; } v; v.f = f;
    unsigned int u = v.u;
    unsigned int r = (u + 0x7fffu + ((u >> 16) & 1u)) >> 16;  // RNE
    return (unsigned short)r;
}
__device__ __forceinline__ float b2f(unsigned short h) {
    union { unsigned int u; float f; } v; v.u = ((unsigned int)h) << 16;
    return v.f;
}
// packed RNE f32x2 -> bf16x2
__device__ __forceinline__ unsigned int cvt_pk_bf16(float lo, float hi) {
    unsigned int r;
    asm("v_cvt_pk_bf16_f32 %0, %1, %2" : "=v"(r) : "v"(lo), "v"(hi));
    return r;
}
// single-instruction 2^x
__device__ __forceinline__ float fast_exp2(float x) {
    float r;
    asm("v_exp_f32 %0, %1" : "=v"(r) : "v"(x));
    return r;
}
// async 16B global->LDS (linear LDS dest; pre-swizzle the SOURCE)
__device__ __forceinline__ void gld_lds16(const void* g, void* l) {
    __builtin_amdgcn_global_load_lds(
        (const __attribute__((address_space(1))) void*)g,
        (__attribute__((address_space(3))) void*)l, 16, 0, 0);
}
// stage a 16KB tile (128 rows x 64 bf16, contiguous rows) into LDS,
// XOR-swizzled: phys = linear ^ ((row&7)<<4) via inverse-swizzled source.
__device__ __forceinline__ void stage16k(const unsigned short* gbase, unsigned short* lbase, int tid) {
#pragma unroll
    for (int p = 0; p < 4; ++p) {
        int d = (p * 256 + tid) * 16;
        int gb = d ^ (((d >> 7) & 7) << 4);
        gld_lds16((const char*)gbase + gb, (char*)lbase + d);
    }
}
// stage a 16KB V tile (64 f-rows x 128 j bf16; global row stride T_SEQ*2 bytes)
// LDS layout: 64 rows x 256B, phys = linear ^ ((f&7)<<4)
__device__ __forceinline__ void stageV16k(const unsigned short* vbase, int jbyte0,
                                          unsigned short* lbase, int tid) {
#pragma unroll
    for (int p = 0; p < 4; ++p) {
        int d = (p * 256 + tid) * 16;
        int f = d >> 8;
        int cb = (d & 255) ^ ((f & 7) << 4);
        gld_lds16((const char*)vbase + (size_t)f * (T_SEQ * 2) + jbyte0 + cb,
                  (char*)lbase + d);
    }
}

// ---------- prep: x, W -> bf16; W^T -> bf16 ----------
__global__ __launch_bounds__(256) void prep_kernel(
    const float* __restrict__ x, const float* __restrict__ W,
    unsigned short* __restrict__ xh,
    unsigned short* __restrict__ Wh, unsigned short* __restrict__ WTh)
{
    const size_t NC = (size_t)NROWS * CDIM;
    const size_t WSZ = (size_t)CDIM * CDIM;
    size_t stride = (size_t)gridDim.x * blockDim.x;
    for (size_t i = (size_t)blockIdx.x * blockDim.x + threadIdx.x; i < NC; i += stride)
        xh[i] = f2bf(x[i]);
    for (size_t i = (size_t)blockIdx.x * blockDim.x + threadIdx.x; i < WSZ; i += stride) {
        unsigned short h = f2bf(W[i]);
        Wh[i] = h;
        size_t k = i / CDIM, c = i % CDIM;
        WTh[c * CDIM + k] = h;
    }
}

// ---------- 128x128 NT bf16 MFMA GEMM (m97 structure): C = A * B^T ----------
// 4 waves, each 64x64 (acc 4x4). gld_lds staging + XOR swizzle.
__global__ __launch_bounds__(256) void gemm128_nt(
    const unsigned short* __restrict__ A, const unsigned short* __restrict__ B,
    float* __restrict__ C, int M, int N, int K, int ldc)
{
    __shared__ unsigned short sA[128 * 64], sB[128 * 64];
    const int tid = threadIdx.x;
    const int lane = tid & 63;
    const int wv = tid >> 6;
    const int wr = wv >> 1, wc = wv & 1;
    const int li = lane & 15, g = lane >> 4;
    const int M0 = blockIdx.y * 128, N0 = blockIdx.x * 128;

    f32x4 acc[4][4];
#pragma unroll
    for (int i = 0; i < 4; ++i)
#pragma unroll
        for (int j = 0; j < 4; ++j) acc[i][j] = (f32x4)0.0f;

    for (int k0 = 0; k0 < K; k0 += 64) {
        __syncthreads();
#pragma unroll
        for (int p = 0; p < 4; ++p) {
            int d = (p * 256 + tid) * 16;
            int row = d >> 7;
            int cb = (d & 127) ^ ((row & 7) << 4);
            gld_lds16((const char*)A + ((size_t)(M0 + row) * K + k0) * 2 + cb, (char*)sA + d);
            gld_lds16((const char*)B + ((size_t)(N0 + row) * K + k0) * 2 + cb, (char*)sB + d);
        }
        __syncthreads();
#pragma unroll
        for (int ks = 0; ks < 2; ++ks) {
            const int ko = ks * 32 + g * 8;
            bf16x8 a[4], b[4];
#pragma unroll
            for (int mi = 0; mi < 4; ++mi) {
                int r = wr * 64 + mi * 16 + li;
                a[mi] = *(const bf16x8*)((char*)sA + ((r * 128 + ko * 2) ^ ((r & 7) << 4)));
            }
#pragma unroll
            for (int ni = 0; ni < 4; ++ni) {
                int r = wc * 64 + ni * 16 + li;
                b[ni] = *(const bf16x8*)((char*)sB + ((r * 128 + ko * 2) ^ ((r & 7) << 4)));
            }
#pragma unroll
            for (int mi = 0; mi < 4; ++mi)
#pragma unroll
                for (int ni = 0; ni < 4; ++ni)
                    acc[mi][ni] = __builtin_amdgcn_mfma_f32_16x16x32_bf16(a[mi], b[ni], acc[mi][ni], 0, 0, 0);
        }
    }
#pragma unroll
    for (int mi = 0; mi < 4; ++mi)
#pragma unroll
        for (int ni = 0; ni < 4; ++ni)
#pragma unroll
            for (int r = 0; r < 4; ++r) {
                int row = M0 + wr * 64 + mi * 16 + g * 4 + r;
                int col = N0 + wc * 64 + ni * 16 + li;
                C[(size_t)row * ldc + col] = acc[mi][ni][r];
            }
}

// ---------- fused RMSNorm + QKV write (q pre-scaled by QSCALE) ----------
__global__ __launch_bounds__(256) void rmsqkv_kernel(
    const float* __restrict__ wbuf,
    const float* __restrict__ g1, const float* __restrict__ g2, const float* __restrict__ g3,
    unsigned short* __restrict__ qb, unsigned short* __restrict__ kb,
    unsigned short* __restrict__ vb)
{
    const int lane = threadIdx.x & 63;
    const int wv = threadIdx.x >> 6;
    const int ridx = blockIdx.x * 4 + wv;
    const int bt = ridx / HEADS;
    const int h = ridx % HEADS;
    const int b = bt >> 11, t = bt & (T_SEQ - 1);

    float v = wbuf[(size_t)bt * CDIM + h * DH + lane];
    float ss = v * v;
#pragma unroll
    for (int m = 32; m; m >>= 1) ss += __shfl_xor(ss, m);
    float r = rsqrtf(ss * (1.0f / 64.0f) + RMS_EPS);
    float wn = v * r;

    size_t o = ((size_t)(b * HEADS + h) * T_SEQ + t) * DH + lane;
    qb[o] = f2bf(wn * g1[lane] * QSCALE);
    kb[o] = f2bf(wn * g2[lane]);
    vb[o] = f2bf(wn * g3[lane]);
}

// ---------- transpose v [bh][t][f] -> vT [bh][f][t] ----------
__global__ __launch_bounds__(256) void vtrans_kernel(
    const unsigned short* __restrict__ vb, unsigned short* __restrict__ vT)
{
    __shared__ unsigned short tile[64][65];
    const int bh = blockIdx.y, t0 = blockIdx.x * 64;
    const int tid = threadIdx.x;
    const int c = tid & 63, r4 = tid >> 6;
#pragma unroll
    for (int i = 0; i < 16; ++i) {
        int rr = r4 + i * 4;
        tile[rr][c] = vb[((size_t)bh * T_SEQ + t0 + rr) * DH + c];
    }
    __syncthreads();
#pragma unroll
    for (int i = 0; i < 16; ++i) {
        int ff = r4 + i * 4;
        vT[((size_t)bh * DH + ff) * T_SEQ + t0 + c] = tile[c][ff];
    }
}

// ---------- pass 1: row/col sums of E = 2^(Q'K^T) -----------------------
// grid (T/128 j-tiles, 4 i-chunks, BH). Wave w owns j rows w*32..+32 (K frags
// in registers). sQ double-buffered via gld_lds; 1 barrier/i-tile.
__global__ __launch_bounds__(256) void sums_kernel(
    const unsigned short* __restrict__ qb, const unsigned short* __restrict__ kb,
    float* __restrict__ rowsum, float* __restrict__ colsum)
{
    __shared__ unsigned short sQ[2][128 * 64];
    const int tid = threadIdx.x;
    const int lane = tid & 63;
    const int w = tid >> 6;
    const int li = lane & 15;
    const int g = lane >> 4;
    const int bh = blockIdx.z;
    const int J0 = blockIdx.x * 128;
    const int IC = blockIdx.y * 512;

    // K fragments (one-time, latency-tolerant scatter)
    bf16x8 kf[2][2];
#pragma unroll
    for (int jb = 0; jb < 2; ++jb)
#pragma unroll
        for (int ks = 0; ks < 2; ++ks)
            kf[jb][ks] = *(const bf16x8*)&kb[((size_t)bh * T_SEQ + J0 + w * 32 + jb * 16 + li) * DH
                                            + ks * 32 + g * 8];

    stage16k(&qb[((size_t)bh * T_SEQ + IC) * DH], sQ[0], tid);
    __syncthreads();

    float csum[2][4];
#pragma unroll
    for (int jb = 0; jb < 2; ++jb)
#pragma unroll
        for (int r = 0; r < 4; ++r) csum[jb][r] = 0.0f;

    for (int it = 0; it < 4; ++it) {
        const int I0 = IC + it * 128;
        if (it + 1 < 4)
            stage16k(&qb[((size_t)bh * T_SEQ + I0 + 128) * DH], sQ[(it + 1) & 1], tid);
        const unsigned short* q = sQ[it & 1];

#pragma unroll
        for (int half = 0; half < 2; ++half) {
            f32x4 acc[2][4];
#pragma unroll
            for (int jb = 0; jb < 2; ++jb)
#pragma unroll
                for (int ib = 0; ib < 4; ++ib) acc[jb][ib] = (f32x4)0.0f;
#pragma unroll
            for (int ks = 0; ks < 2; ++ks) {
                const int ko = ks * 32 + g * 8;
#pragma unroll
                for (int ib = 0; ib < 4; ++ib) {
                    int qr = half * 64 + ib * 16 + li;
                    bf16x8 qf = *(const bf16x8*)((const char*)q + ((qr * 128 + ko * 2) ^ ((qr & 7) << 4)));
#pragma unroll
                    for (int jb = 0; jb < 2; ++jb)
                        acc[jb][ib] = __builtin_amdgcn_mfma_f32_16x16x32_bf16(kf[jb][ks], qf, acc[jb][ib], 0, 0, 0);
                }
            }
#pragma unroll
            for (int ib = 0; ib < 4; ++ib) {
                float rp = 0.0f;
#pragma unroll
                for (int jb = 0; jb < 2; ++jb)
#pragma unroll
                    for (int r = 0; r < 4; ++r) {
                        float e = fast_exp2(acc[jb][ib][r]);
                        csum[jb][r] += e;
                        rp += e;
                    }
                rp += __shfl_xor(rp, 16);
                rp += __shfl_xor(rp, 32);      // sum over this wave's 32 j
                if (g == 0)
                    atomicAdd(&rowsum[(size_t)bh * T_SEQ + I0 + half * 64 + ib * 16 + li], rp);
            }
        }
        __syncthreads();   // drains next-tile stage (hidden under compute)
    }
    // colsum: reduce over the 16 i-lanes, one atomic per j
#pragma unroll
    for (int jb = 0; jb < 2; ++jb)
#pragma unroll
        for (int r = 0; r < 4; ++r) {
            float c = csum[jb][r];
            c += __shfl_xor(c, 1); c += __shfl_xor(c, 2);
            c += __shfl_xor(c, 4); c += __shfl_xor(c, 8);
            if (li == 0)
                atomicAdd(&colsum[(size_t)bh * T_SEQ + J0 + w * 32 + jb * 16 + g * 4 + r], c);
        }
}

// ---------- 1/x for row/col sums ----------
__global__ __launch_bounds__(256) void inv_kernel(
    const float* __restrict__ rs, const float* __restrict__ cs,
    float* __restrict__ ri, float* __restrict__ ci_, int n)
{
    int i = blockIdx.x * 256 + threadIdx.x;
    if (i < n) { ri[i] = 1.0f / rs[i]; ci_[i] = 1.0f / cs[i]; }
}

// ---------- pass 2: swapped QK^T + scale + PV; K,V double-buffered ---------
// grid (T/64 i-tiles, JS j-chunks, BH). Wave w owns 16 i-rows.
// ONE barrier per tile: { sync; stage(t+1 -> buf^1); QKT+pack+PV on buf }.
__global__ __launch_bounds__(256) void fused_pv_kernel(
    const unsigned short* __restrict__ qb, const unsigned short* __restrict__ kb,
    const unsigned short* __restrict__ vT,
    const float* __restrict__ rowinv, const float* __restrict__ colinv,
    float* __restrict__ ypart)
{
    __shared__ unsigned short sK[2][128 * 64];   // 32 KB
    __shared__ unsigned short sV[2][64 * 128];   // 32 KB: [f][128 j]
    __shared__ unsigned short sP[64 * 128];      // 16 KB, rows private per wave

    const int tid = threadIdx.x;
    const int lane = tid & 63;
    const int w = tid >> 6;
    const int li = lane & 15;
    const int g = lane >> 4;
    const int bh = blockIdx.z;
    const int jc = blockIdx.y;
    const int I0 = blockIdx.x * 64;
    const int J0 = jc * (T_SEQ / JS);
    constexpr int NT = T_SEQ / JS / 128;   // 8

    // Q fragments in registers, loaded once (pre-scaled by QSCALE)
    const int qrow = I0 + w * 16 + li;
    bf16x8 qf[2];
#pragma unroll
    for (int ks = 0; ks < 2; ++ks)
        qf[ks] = *(const bf16x8*)&qb[((size_t)bh * T_SEQ + qrow) * DH + ks * 32 + g * 8];
    const float rv = rowinv[bh * T_SEQ + qrow];

    const int prow = w * 16 + li;
    const int pkey = (prow & 7) << 4;

    f32x4 accy[4];
#pragma unroll
    for (int i = 0; i < 4; ++i) accy[i] = (f32x4)0.0f;

    const unsigned short* kt0 = &kb[((size_t)bh * T_SEQ + J0) * DH];
    const unsigned short* vb0 = &vT[(size_t)bh * DH * T_SEQ];

    // prologue: stage K(0), V(0) into buf 0
    stage16k(kt0, sK[0], tid);
    stageV16k(vb0, J0 * 2, sV[0], tid);

    int buf = 0;
    for (int jt = 0; jt < NT; ++jt) {
        __syncthreads();   // drains stages targeting buf (issued prev iter / prologue)
        if (jt + 1 < NT) {
            stage16k(kt0 + (size_t)(jt + 1) * 128 * DH, sK[buf ^ 1], tid);
            stageV16k(vb0, (J0 + (jt + 1) * 128) * 2, sV[buf ^ 1], tid);
        }

        // --- QK^T from sK[buf] (swapped: rows = j, cols = i) ---
        f32x4 accs[8];
#pragma unroll
        for (int jb = 0; jb < 8; ++jb) accs[jb] = (f32x4)0.0f;
#pragma unroll
        for (int ks = 0; ks < 2; ++ks) {
            const int ko = ks * 32 + g * 8;
#pragma unroll
            for (int jb = 0; jb < 8; ++jb) {
                int jr = jb * 16 + li;
                bf16x8 kfr = *(const bf16x8*)((char*)sK[buf] + ((jr * 128 + ko * 2) ^ ((jr & 7) << 4)));
                accs[jb] = __builtin_amdgcn_mfma_f32_16x16x32_bf16(kfr, qf[ks], accs[jb], 0, 0, 0);
            }
        }

        // --- pack: P = 2^S' * (rinv_i + cinv_j) -> bf16 -> sP (own rows) ---
#pragma unroll
        for (int jb = 0; jb < 8; ++jb) {
            f32x4 cv = *(const f32x4*)&colinv[(size_t)bh * T_SEQ + J0 + jt * 128 + jb * 16 + g * 4];
            float p0 = fast_exp2(accs[jb][0]) * (rv + cv[0]);
            float p1 = fast_exp2(accs[jb][1]) * (rv + cv[1]);
            float p2 = fast_exp2(accs[jb][2]) * (rv + cv[2]);
            float p3 = fast_exp2(accs[jb][3]) * (rv + cv[3]);
            uint2 pw;
            pw.x = cvt_pk_bf16(p0, p1);
            pw.y = cvt_pk_bf16(p2, p3);
            int off = (prow * 256 + jb * 32 + g * 8) ^ pkey;
            *(uint2*)((char*)sP + off) = pw;
        }

        // --- PV: y[i][f] += P[i][j] * V^T[f][j], both from LDS ---
#pragma unroll
        for (int ks2 = 0; ks2 < 4; ++ks2) {
            bf16x8 pf = *(const bf16x8*)((char*)sP + ((prow * 256 + ks2 * 64 + g * 16) ^ pkey));
#pragma unroll
            for (int ni = 0; ni < 4; ++ni) {
                int vrow = ni * 16 + li;
                bf16x8 vf = *(const bf16x8*)((char*)sV[buf] + ((vrow * 256 + ks2 * 64 + g * 16) ^ ((vrow & 7) << 4)));
                accy[ni] = __builtin_amdgcn_mfma_f32_16x16x32_bf16(pf, vf, accy[ni], 0, 0, 0);
            }
        }
        buf ^= 1;
    }

    // store f32 partial: ypart[jc][bh][i][f]
#pragma unroll
    for (int ni = 0; ni < 4; ++ni)
#pragma unroll
        for (int r = 0; r < 4; ++r) {
            int i = I0 + w * 16 + g * 4 + r;
            int f = ni * 16 + li;
            ypart[(((size_t)jc * BH_TOT + bh) * T_SEQ + i) * DH + f] = accy[ni][r];
        }
}

// ---------- reduce JS partials -> bf16 y ----------
__global__ __launch_bounds__(256) void reduce_kernel(
    const float* __restrict__ ypart, unsigned short* __restrict__ yh)
{
    const size_t STR = (size_t)BH_TOT * T_SEQ * DH;
    size_t idx = (size_t)blockIdx.x * 256 + threadIdx.x;   // one per 4 elems
    if (idx >= STR / 4) return;
    f32x4 a = *(const f32x4*)&ypart[idx * 4];
    f32x4 b = *(const f32x4*)&ypart[STR + idx * 4];
    int e = (int)(idx * 4);
    int f = e & 63;
    int rrow = e >> 6;
    int t = rrow & (T_SEQ - 1);
    int bh = rrow >> 11;
    int b_ = bh / HEADS, h = bh % HEADS;
    size_t o = ((size_t)b_ * T_SEQ + t) * CDIM + h * DH + f;
#pragma unroll
    for (int q = 0; q < 4; ++q)
        yh[o + q] = f2bf(a[q] + b[q]);
}

// ---------- host ----------
extern "C" void kernel_launch(void* const* d_in, const int* in_sizes, int n_in,
                              void* d_out, int out_size, void* d_ws, size_t ws_size,
                              hipStream_t stream)
{
    const float* x  = (const float*)d_in[0];
    const float* W  = (const float*)d_in[1];
    const float* g1 = (const float*)d_in[2];
    const float* g2 = (const float*)d_in[3];
    const float* g3 = (const float*)d_in[4];
    float* out = (float*)d_out;

    char* p = (char*)d_ws;
    auto alloc = [&](size_t bytes) -> void* {
        void* r = (void*)p;
        p += (bytes + 255) & ~(size_t)255;
        return r;
    };
    const size_t NC  = (size_t)NROWS * CDIM;
    const size_t WSZ = (size_t)CDIM * CDIM;
    const size_t QSZ = (size_t)BH_TOT * T_SEQ * DH;

    unsigned short* xh   = (unsigned short*)alloc(NC * 2);
    unsigned short* Wh   = (unsigned short*)alloc(WSZ * 2);
    unsigned short* WTh  = (unsigned short*)alloc(WSZ * 2);
    float*          wbuf = (float*)alloc(NC * 4);
    unsigned short* qb   = (unsigned short*)alloc(QSZ * 2);
    unsigned short* kb   = (unsigned short*)alloc(QSZ * 2);
    unsigned short* vb   = (unsigned short*)alloc(QSZ * 2);
    unsigned short* vT   = (unsigned short*)alloc(QSZ * 2);
    unsigned short* yh   = (unsigned short*)alloc(NC * 2);
    float* ypart  = (float*)alloc((size_t)JS * QSZ * 4);
    float* rowsum = (float*)alloc((size_t)BH_TOT * T_SEQ * 4);
    float* colsum = (float*)alloc((size_t)BH_TOT * T_SEQ * 4);
    float* rowinv = (float*)alloc((size_t)BH_TOT * T_SEQ * 4);
    float* colinv = (float*)alloc((size_t)BH_TOT * T_SEQ * 4);

    prep_kernel<<<2048, 256, 0, stream>>>(x, W, xh, Wh, WTh);
    gemm128_nt<<<dim3(CDIM / 128, NROWS / 128), 256, 0, stream>>>(
        xh, Wh, wbuf, NROWS, CDIM, CDIM, CDIM);
    rmsqkv_kernel<<<(NROWS * HEADS) / 4, 256, 0, stream>>>(
        wbuf, g1, g2, g3, qb, kb, vb);
    vtrans_kernel<<<dim3(T_SEQ / 64, BH_TOT), 256, 0, stream>>>(vb, vT);

    hipMemsetAsync(rowsum, 0, (size_t)BH_TOT * T_SEQ * 4, stream);
    hipMemsetAsync(colsum, 0, (size_t)BH_TOT * T_SEQ * 4, stream);
    sums_kernel<<<dim3(T_SEQ / 128, 4, BH_TOT), 256, 0, stream>>>(
        qb, kb, rowsum, colsum);
    int n = BH_TOT * T_SEQ;
    inv_kernel<<<(n + 255) / 256, 256, 0, stream>>>(rowsum, colsum, rowinv, colinv, n);

    fused_pv_kernel<<<dim3(T_SEQ / 64, JS, BH_TOT), 256, 0, stream>>>(
        qb, kb, vT, rowinv, colinv, ypart);
    {
        size_t n4 = (size_t)BH_TOT * T_SEQ * DH / 4;
        reduce_kernel<<<(unsigned)((n4 + 255) / 256), 256, 0, stream>>>(ypart, yh);
    }

    gemm128_nt<<<dim3(CDIM / 128, NROWS / 128), 256, 0, stream>>>(
        yh, WTh, out, NROWS, CDIM, CDIM, CDIM);
}